// Round 21
// baseline (91.460 us; speedup 1.0000x reference)
//
#include <hip/hip_runtime.h>
#include <hip/hip_bf16.h>

// Problem: T=2048, B=32, H=512
//   scores[b,t] = sum_o v[o] * tanh( hb[b,o] + sum_h enc[t,b,h] * W2[o,h] )
//   out[b,0,t]  = softmax_t(scores[b,:])
//
// R21: A staged as RAW FP32 directly from enc via global_load_lds with
// XOR-pre-swizzled PER-LANE SOURCE addresses (dest linear — rule #21);
// fp32->bf16 conversion happens at fragment-read time (2x ds_read_b128 +
// 4 cvt_pk, 2-way banks = free). B via fragment-major W2p image (contiguous
// 1KB wave reads). BK=32, dbuf, 49KB LDS -> 3 blocks/CU. No conversion pass.
// Rationale: R17/18 proved the all-gload_lds main runs ~12-16us (vs 92-95
// for every reg-staged-A variant); its only cost was the 80us enc-image
// pass. This keeps the fast main structure and deletes the pass.
//
// HARD-WON RULES (R2..R20): WRITE>>2MB on MAIN = spill; gload_lds dest is
// wave-uniform+lane*16B (per-wave distinct dests), SOURCE is per-lane;
// occupancy alone not the lever; counted vmcnt/setprio negative on 2-phase;
// standalone conversion passes stall at ~1.5TB/s — never add one.

#define TT 2048
#define BB 32
#define HH 512

typedef __attribute__((ext_vector_type(8))) short bf16x8;
typedef __attribute__((ext_vector_type(4))) float f32x4;

static __device__ __forceinline__ unsigned cvt2(float a, float b) {
    union { __hip_bfloat162 h; unsigned u; } cv;
    cv.h = __float22bfloat162_rn(make_float2(a, b));   // v_cvt_pk_bf16_f32
    return cv.u;
}

static __device__ __forceinline__ unsigned short f2bf(float f) {
    unsigned int u = __float_as_uint(f);
    unsigned int r = (u + 0x7FFFu + ((u >> 16) & 1u)) >> 16;  // RNE
    return (unsigned short)r;
}

// tanh(x) = 1 - 2/(1+e^{2x});  inf-safe at both ends.
static __device__ __forceinline__ float fast_tanh(float x) {
    float e = __expf(2.0f * x);
    return 1.0f - 2.0f * __builtin_amdgcn_rcpf(1.0f + e);
}

static __device__ __forceinline__ void gload_lds16(const void* g, void* l) {
    __builtin_amdgcn_global_load_lds(
        (const __attribute__((address_space(1))) unsigned int*)g,
        (__attribute__((address_space(3))) unsigned int*)l, 16, 0, 0);
}

// ---- Kernel 1 (prep): blocks [0,1024) pack W2 into FRAGMENT-MAJOR image;
// blocks [1024,1088) compute hb.
// W2p layout: idx -> e=idx&7, lane=(idx>>3)&63, cb=(idx>>9)&7, ks=(idx>>12)&15,
// nt=idx>>16.  Element = W2[o = nt*128 + cb*16 + (lane&15)]
//                          [k = ks*32 + (lane>>4)*8 + e]
// so slot (nt,ks,cb) is one contiguous 1KB wave fragment read.
__global__ void prep_kernel(const float* __restrict__ W,
                            const float* __restrict__ hidden,
                            const float* __restrict__ b_attn,
                            short* __restrict__ W2p,
                            float* __restrict__ hb) {
    __shared__ float hrow[512];
    const int bid = blockIdx.x;
    if (bid < 1024) {
        int idx = bid * 256 + threadIdx.x;      // 262144 total
        int e    = idx & 7;
        int lane = (idx >> 3) & 63;
        int cb   = (idx >> 9) & 7;
        int ks   = (idx >> 12) & 15;
        int nt   = idx >> 16;
        int o = nt * 128 + cb * 16 + (lane & 15);
        int k = ks * 32 + (lane >> 4) * 8 + e;
        W2p[idx] = (short)f2bf(W[o * 1024 + 512 + k]);
    } else {
        const int hbid = bid - 1024;
        int b = hbid >> 1;
        int o = ((hbid & 1) << 8) + threadIdx.x;
        for (int h = threadIdx.x; h < 512; h += 256) hrow[h] = hidden[b * 512 + h];
        __syncthreads();
        const float4* wr = reinterpret_cast<const float4*>(W + (size_t)o * 1024);
        const float4* hr = reinterpret_cast<const float4*>(hrow);
        float acc = b_attn[o];
#pragma unroll 8
        for (int i = 0; i < 128; ++i) {
            float4 w = wr[i], h4 = hr[i];
            acc += w.x * h4.x + w.y * h4.y + w.z * h4.z + w.w * h4.w;
        }
        hb[b * 512 + o] = acc;
    }
}

// ---- Kernel 2: 128x128 tile, BK=32, 16 K-steps, all-gload_lds staging.
// M-rows contiguous r = t*32+b (R20-verified indexing). Grid 2048, XCD remap.
// 256 thr / 4 waves (wr x wc = 2x2), wave tile 64x64, acc[4][4].
// A: fp32 [128][32] in LDS, chunk-swizzled via PER-LANE SOURCE XOR:
//    As[row][chunk c] holds source k-chunk (c ^ (row&7)) (16B chunks).
//    Fragment read: 2x ds_read_b128 fp32 + 4 cvt_pk -> bf16x8 (2-way banks).
// B: fragment-major W2p slots, 1KB contiguous per (ks, col-block).
__global__ __launch_bounds__(256, 2) void attn_main_kernel(
    const float* __restrict__ enc, const short* __restrict__ W2p,
    const float* __restrict__ hb, const float* __restrict__ v,
    float* __restrict__ scores_part)
{
    __shared__ float Asf[2][128 * 32];   // 16KB x2 fp32, source-XOR swizzled
    __shared__ short Bs[2][8 * 512];     // 8KB x2 bf16, fragment-major
    __shared__ float s_red[2][128];

    const int tid = threadIdx.x;
    const int bid = blockIdx.x;
    const int w = (bid & 7) * 256 + (bid >> 3);  // XCD-contiguous (bijective)
    const int nt = w & 3;                // N-tile (128 o-cols)
    const int mtile = w >> 2;            // 512 M-tiles
    const int r0 = mtile * 128;          // contiguous global row base (r = t*32+b)

    const int wave = tid >> 6;
    const int lane = tid & 63;
    const int wr = wave >> 1;            // row half (64 rows)
    const int wc = wave & 1;             // col half (64 cols)
    const int lcol = lane & 15;
    const int lq = lane >> 4;

    // A staging: wave stages rows wave*32..+32; inst j covers 8 rows (1KB).
    // Lane l -> dest row (base + l>>3), dest chunk (l&7); source chunk
    // pre-XOR'd: (l&7) ^ ((l>>3)&7)  (row&7 == (l>>3)&7 since j*8 ≡ 0 mod 8).
    const int arowl = wave * 32 + (lane >> 3);
    const float* asrc = enc + (size_t)(r0 + arowl) * HH +
                        (((lane & 7) ^ ((lane >> 3) & 7)) << 2);
    // B staging: wave stages slots wave*2, wave*2+1 of the step's 8 slots.
    const short* bsrc = W2p + (size_t)nt * 65536 + (wave * 2) * 512 + lane * 8;

    f32x4 acc[4][4];
#pragma unroll
    for (int mt = 0; mt < 4; ++mt)
#pragma unroll
        for (int ns = 0; ns < 4; ++ns) acc[mt][ns] = (f32x4){0.f, 0.f, 0.f, 0.f};

#define STAGE_A(KS, BUF)                                                            \
    {                                                                               \
        _Pragma("unroll")                                                           \
        for (int j = 0; j < 4; ++j)                                                 \
            gload_lds16(asrc + j * 8 * HH + (KS) * 32,                              \
                        &Asf[BUF][(wave * 32 + j * 8) * 32]);                       \
    }

#define STAGE_B(KS, BUF)                                                            \
    {                                                                               \
        const short* s0 = bsrc + (KS) * 8 * 512;                                    \
        gload_lds16(s0,       &Bs[BUF][(wave * 2) * 512]);                          \
        gload_lds16(s0 + 512, &Bs[BUF][(wave * 2 + 1) * 512]);                      \
    }

#define COMPUTE(BUF)                                                                \
    {                                                                               \
        bf16x8 af[4], bfr[4];                                                       \
        _Pragma("unroll")                                                           \
        for (int mt = 0; mt < 4; ++mt) {                                            \
            const int row = wr * 64 + mt * 16 + lcol;                               \
            const int x = row & 7;                                                  \
            const float4 v0 = *reinterpret_cast<const float4*>(                     \
                &Asf[BUF][row * 32 + (((2 * lq) ^ x) << 2)]);                       \
            const float4 v1 = *reinterpret_cast<const float4*>(                     \
                &Asf[BUF][row * 32 + ((((2 * lq) | 1) ^ x) << 2)]);                 \
            union { bf16x8 v8; uint4 u; } pk;                                       \
            pk.u.x = cvt2(v0.x, v0.y);                                              \
            pk.u.y = cvt2(v0.z, v0.w);                                              \
            pk.u.z = cvt2(v1.x, v1.y);                                              \
            pk.u.w = cvt2(v1.z, v1.w);                                              \
            af[mt] = pk.v8;                                                         \
        }                                                                           \
        _Pragma("unroll")                                                           \
        for (int ns = 0; ns < 4; ++ns)                                              \
            bfr[ns] = *reinterpret_cast<const bf16x8*>(                             \
                &Bs[BUF][(wc * 4 + ns) * 512 + lane * 8]);                          \
        _Pragma("unroll")                                                           \
        for (int mt = 0; mt < 4; ++mt)                                              \
            _Pragma("unroll")                                                       \
            for (int ns = 0; ns < 4; ++ns)                                          \
                acc[mt][ns] = __builtin_amdgcn_mfma_f32_16x16x32_bf16(              \
                    af[mt], bfr[ns], acc[mt][ns], 0, 0, 0);                         \
    }

    // ---- prologue: stage step 0 into buf0
    STAGE_A(0, 0);
    STAGE_B(0, 0);
    __syncthreads();

    // ---- 16 K-steps, hand-unrolled x2, static ping-pong
#pragma unroll
    for (int s2 = 0; s2 < 8; ++s2) {
        const int s = s2 * 2;
        STAGE_A(s + 1, 1);            // s+1 <= 15 always
        STAGE_B(s + 1, 1);
        COMPUTE(0);
        __syncthreads();
        if (s + 2 < 16) {
            STAGE_A(s + 2, 0);
            STAGE_B(s + 2, 0);
        }
        COMPUTE(1);
        __syncthreads();
    }

    // ---- epilogue: tanh + v-dot; b = (local row)&31 per row (wr*64 ≡ 0 mod 32)
    float part[4][4];
#pragma unroll
    for (int mt = 0; mt < 4; ++mt)
#pragma unroll
        for (int j = 0; j < 4; ++j) part[mt][j] = 0.0f;

#pragma unroll
    for (int ns = 0; ns < 4; ++ns) {
        const int o = nt * 128 + wc * 64 + ns * 16 + lcol;
        const float vv = v[o];
        const float* hbcol = hb + o;
#pragma unroll
        for (int mt = 0; mt < 4; ++mt) {
            const int bbase = (mt * 16 + lq * 4) & 31;
#pragma unroll
            for (int j = 0; j < 4; ++j) {
                const float hbv = hbcol[(bbase + j) * 512];
                const float x = acc[mt][ns][j] + hbv;
                part[mt][j] = fmaf(fast_tanh(x), vv, part[mt][j]);
            }
        }
    }

#pragma unroll
    for (int off = 1; off < 16; off <<= 1)
#pragma unroll
        for (int mt = 0; mt < 4; ++mt)
#pragma unroll
            for (int j = 0; j < 4; ++j)
                part[mt][j] += __shfl_xor(part[mt][j], off, 64);

    if (lcol == 0) {
#pragma unroll
        for (int mt = 0; mt < 4; ++mt)
#pragma unroll
            for (int j = 0; j < 4; ++j)
                s_red[wc][wr * 64 + mt * 16 + lq * 4 + j] = part[mt][j];
    }
    __syncthreads();

    // scores_part stored in r-order: sp[nt*65536 + r]
    if (tid < 128)
        scores_part[(size_t)nt * (TT * BB) + r0 + tid] =
            s_red[0][tid] + s_red[1][tid];
}

// ---- Kernel 3: sum 4 N-tile partials + softmax over T per b (r-ordered sp).
__global__ void softmax_kernel(const float* __restrict__ sp, float* __restrict__ out) {
    __shared__ float wred[4];
    __shared__ float wsum[4];
    const int b = blockIdx.x;
    const int tid = threadIdx.x;   // 256
    float vals[8];
    float mx = -1e30f;
#pragma unroll
    for (int i = 0; i < 8; ++i) {
        const int t = i * 256 + tid;
        const size_t r = (size_t)t * BB + b;
        const float s = sp[r] + sp[(size_t)(TT * BB) + r] +
                        sp[(size_t)2 * (TT * BB) + r] + sp[(size_t)3 * (TT * BB) + r];
        vals[i] = s;
        mx = fmaxf(mx, s);
    }
#pragma unroll
    for (int off = 32; off; off >>= 1) mx = fmaxf(mx, __shfl_xor(mx, off, 64));
    if ((tid & 63) == 0) wred[tid >> 6] = mx;
    __syncthreads();
    mx = fmaxf(fmaxf(wred[0], wred[1]), fmaxf(wred[2], wred[3]));
    float s = 0.0f;
#pragma unroll
    for (int i = 0; i < 8; ++i) {
        vals[i] = __expf(vals[i] - mx);
        s += vals[i];
    }
#pragma unroll
    for (int off = 32; off; off >>= 1) s += __shfl_xor(s, off, 64);
    if ((tid & 63) == 0) wsum[tid >> 6] = s;
    __syncthreads();
    s = wsum[0] + wsum[1] + wsum[2] + wsum[3];
    const float inv = 1.0f / s;
#pragma unroll
    for (int i = 0; i < 8; ++i) out[b * TT + i * 256 + tid] = vals[i] * inv;
}

extern "C" void kernel_launch(void* const* d_in, const int* in_sizes, int n_in,
                              void* d_out, int out_size, void* d_ws, size_t ws_size,
                              hipStream_t stream) {
    const float* hidden = (const float*)d_in[0];   // (1,B,H)
    const float* enc    = (const float*)d_in[1];   // (T,B,H)
    const float* W      = (const float*)d_in[2];   // (H,2H)
    const float* b_attn = (const float*)d_in[3];   // (H,)
    const float* v      = (const float*)d_in[4];   // (H,)
    float* out = (float*)d_out;                    // (B,1,T)

    char* base = (char*)d_ws;
    short* W2p = (short*)base;                          // 524288 B
    float* hb  = (float*)(base + 524288);               // 65536 B
    float* sp  = (float*)(base + 589824);               // 4*65536*4 = 1048576 B

    prep_kernel<<<1088, 256, 0, stream>>>(W, hidden, b_attn, W2p, hb);
    attn_main_kernel<<<2048, 256, 0, stream>>>(enc, W2p, hb, v, sp);
    softmax_kernel<<<32, 256, 0, stream>>>(sp, out);
}